// Round 28
// baseline (86.498 us; speedup 1.0000x reference)
//
#include <hip/hip_runtime.h>
#include <cstdint>
#include <cstddef>

typedef unsigned short u16;
typedef __bf16 bf16x8 __attribute__((ext_vector_type(8)));
typedef float  f32x4  __attribute__((ext_vector_type(4)));
typedef float  f32x16 __attribute__((ext_vector_type(16)));
typedef unsigned u32x4 __attribute__((ext_vector_type(4)));

#define DEV __device__ __forceinline__

#define B_  2
#define S_  2048
#define DM  1024
#define H_  16
#define DK  64
#define M_  (B_ * S_)   // 4096

#if __has_builtin(__builtin_amdgcn_exp2f)
#define EXP2(x) __builtin_amdgcn_exp2f(x)
#else
#define EXP2(x) exp2f(x)
#endif

// ---------------- workspace layout (bytes) ----------------
constexpr size_t OFF_QBF  = 0;                                  // Q proj out bf16 [M][DM]
constexpr size_t OFF_KF   = OFF_QBF  + (size_t)M_ * DM * 2;     // K frag-linear (sigma rows)
constexpr size_t OFF_VF   = OFF_KF   + (size_t)M_ * DK * 2;     // V frag-linear
constexpr size_t OFF_AOBF = OFF_VF   + (size_t)M_ * DK * 2;     // attn out bf16 [M][DM]
constexpr size_t OFF_WQT  = OFF_AOBF + (size_t)M_ * DM * 2;     // Wq^T bf16 [DM][DM]
constexpr size_t OFF_WOT  = OFF_WQT  + (size_t)DM * DM * 2;     // Wo^T bf16 [DM][DM]
constexpr size_t OFF_WKT  = OFF_WOT  + (size_t)DM * DM * 2;     // Wk^T bf16 [DK][DM]
constexpr size_t OFF_WVT  = OFF_WKT  + (size_t)DK * DM * 2;     // Wv^T bf16 [DK][DM]
constexpr size_t OFF_XQBF = OFF_WVT  + (size_t)DK * DM * 2;     // inputs_q bf16 [M][DM]

// ---------------- helpers ----------------
DEV u16 f2bf(float f) {                 // RNE f32 -> bf16
  unsigned u = __float_as_uint(f);
  u += 0x7fffu + ((u >> 16) & 1u);
  return (u16)(u >> 16);
}

DEV unsigned cvtpk(float lo, float hi) { // pack 2 f32 -> 2 bf16 (lo in low 16)
  return (unsigned)f2bf(lo) | ((unsigned)f2bf(hi) << 16);
}

DEV unsigned cvtpk_hw(float lo, float hi) { // v_cvt_pk_bf16_f32 (1 instr)
  unsigned r;
  asm("v_cvt_pk_bf16_f32 %0, %1, %2" : "=v"(r) : "v"(lo), "v"(hi));
  return r;
}

DEV u32x4 pack8(const float4& a, const float4& b) {
  u32x4 w;
  w[0] = cvtpk(a.x, a.y);
  w[1] = cvtpk(a.z, a.w);
  w[2] = cvtpk(b.x, b.y);
  w[3] = cvtpk(b.z, b.w);
  return w;
}

DEV void gload_lds16(const void* g, void* l) {
  __builtin_amdgcn_global_load_lds(
      (const __attribute__((address_space(1))) unsigned int*)g,
      (__attribute__((address_space(3))) unsigned int*)l, 16, 0, 0);
}

// ---------------- shared-memory views for the fused qkv kernel ----------------
struct GemmSmem { u16 At[2][128 * 64]; u16 Bt[2][64 * 64]; };      // 48 KB
struct KvSmem   { u16 At[2][64 * 64]; u16 Bt[2][64 * 64]; u16 stage[64][72]; }; // ~41 KB
union QkvSmem { GemmSmem g; KvSmem kv; };

// ---------------- merged prep: 4 weight transposes + in_q cast, one launch ----------------
__global__ __launch_bounds__(256) void prep_kernel(
    const float* __restrict__ Wq, const float* __restrict__ Wo,
    const float* __restrict__ Wk, const float* __restrict__ Wv,
    const float* __restrict__ in_q,
    u16* __restrict__ WqT, u16* __restrict__ WoT,
    u16* __restrict__ WkT, u16* __restrict__ WvT,
    u16* __restrict__ Xq) {
  const int z = blockIdx.z;
  if (z == 4) {                        // cast in_q: 4M f32 -> bf16
    const int tid = (blockIdx.y * 32 + blockIdx.x) * 256 +
                    threadIdx.y * 32 + threadIdx.x;
    const int n8 = M_ * DM / 8;
    for (int i = tid; i < n8; i += 1024 * 256) {
      float4 a = ((const float4*)in_q)[2 * i];
      float4 b = ((const float4*)in_q)[2 * i + 1];
      ((u32x4*)Xq)[i] = pack8(a, b);
    }
    return;
  }
  const float* W; u16* WT; int C;
  if (z == 0)      { W = Wq; WT = WqT; C = DM; }
  else if (z == 1) { W = Wo; WT = WoT; C = DM; }
  else if (z == 2) { W = Wk; WT = WkT; C = DK; }
  else             { W = Wv; WT = WvT; C = DK; }
  const int c0 = blockIdx.x * 32, r0 = blockIdx.y * 32;
  if (c0 >= C) return;                 // block-uniform exit (Wk/Wv: only x<2)
  __shared__ u16 tile[32][33];
  for (int i = threadIdx.y; i < 32; i += 8)
    tile[i][threadIdx.x] = f2bf(W[(size_t)(r0 + i) * C + c0 + threadIdx.x]);
  __syncthreads();
  for (int i = threadIdx.y; i < 32; i += 8)
    WT[(size_t)(c0 + i) * DM + r0 + threadIdx.x] = tile[threadIdx.x][i];
}

// ---------------- K/V projection body: 2-phase dbuf BK=64, fused frag-linear emit ----------------
DEV void kvproj_dev(KvSmem& sm,
                    const float* __restrict__ X, const u16* __restrict__ WT,
                    const float* __restrict__ bias,
                    u16* __restrict__ KF, u16* __restrict__ VF,
                    int bm, int sel) {
  const int tid = threadIdx.x, wave = tid >> 6, lane = tid & 63;
  const int g = lane >> 4, c = lane & 15;
  const int wm = wave >> 1, wn = wave & 1;
  f32x4 acc[2][2] = {};

  // A: reg-staged f32 -> bf16, write-side XOR swizzle (8 slots of 8 bf16/row)
  const int row = tid >> 2, sd = tid & 3;
  const int s0 = sd, s1 = sd + 4;
  const float* Asrc = X + (size_t)(bm * 64 + row) * DM;
  const int d0 = row * 64 + ((s0 ^ (row & 7)) * 8);
  const int d1 = row * 64 + ((s1 ^ (row & 7)) * 8);
  float4 ar0, ar1, ar2, ar3;                       // 16 f32 in flight

  // B: gemm-style pre-swizzled-source gload_lds map (2 slots/thread)
  int brow[2], bcol[2];
#pragma unroll
  for (int i = 0; i < 2; ++i) {
    const int sid = (i * 4 + wave) * 64 + lane;    // 0..511
    brow[i] = sid >> 3;
    bcol[i] = ((sid & 7) ^ ((sid >> 3) & 7)) * 8;
  }

  auto loadA = [&](int t) {
    const float* p = Asrc + (t << 6);
    ar0 = *(const float4*)(p + s0 * 8);
    ar1 = *(const float4*)(p + s0 * 8 + 4);
    ar2 = *(const float4*)(p + s1 * 8);
    ar3 = *(const float4*)(p + s1 * 8 + 4);
  };
  auto writeA = [&](int buf) {
    *(u32x4*)&sm.At[buf][d0] = pack8(ar0, ar1);
    *(u32x4*)&sm.At[buf][d1] = pack8(ar2, ar3);
  };
  auto stageB = [&](int buf, int t) {
#pragma unroll
    for (int i = 0; i < 2; ++i)
      gload_lds16(WT + (size_t)brow[i] * DM + (t << 6) + bcol[i],
                  &sm.Bt[buf][(i * 4 + wave) * 512]);
  };

  const int nt = DM >> 6;   // 16
  loadA(0);
  stageB(0, 0);
  asm volatile("s_waitcnt vmcnt(0)" ::: "memory");
  writeA(0);
  __syncthreads();

  int cur = 0;
  for (int t = 0; t < nt; ++t) {
    if (t + 1 < nt) { stageB(cur ^ 1, t + 1); loadA(t + 1); }
#pragma unroll
    for (int kk = 0; kk < 2; ++kk) {
      bf16x8 af[2], bfr[2];
#pragma unroll
      for (int mf = 0; mf < 2; ++mf) {
        const int ra = wm * 32 + mf * 16 + c;
        af[mf] = *(const bf16x8*)(&sm.At[cur][ra * 64 + ((kk * 4 + g) ^ (ra & 7)) * 8]);
      }
#pragma unroll
      for (int nf = 0; nf < 2; ++nf) {
        const int rb = wn * 32 + nf * 16 + c;
        bfr[nf] = *(const bf16x8*)(&sm.Bt[cur][rb * 64 + ((kk * 4 + g) ^ (rb & 7)) * 8]);
      }
#pragma unroll
      for (int mf = 0; mf < 2; ++mf)
#pragma unroll
        for (int nf = 0; nf < 2; ++nf)
          acc[mf][nf] = __builtin_amdgcn_mfma_f32_16x16x32_bf16(
              af[mf], bfr[nf], acc[mf][nf], 0, 0, 0);
    }
    asm volatile("s_waitcnt vmcnt(0)" ::: "memory");  // next B tile landed
    if (t + 1 < nt) writeA(cur ^ 1);
    __syncthreads();
    cur ^= 1;
  }

  // stage D-layout output (bias added) into LDS
#pragma unroll
  for (int nf = 0; nf < 2; ++nf) {
    const int col = wn * 32 + nf * 16 + c;
    const float bs = bias[col];
#pragma unroll
    for (int mf = 0; mf < 2; ++mf)
#pragma unroll
      for (int r = 0; r < 4; ++r)
        sm.stage[wm * 32 + mf * 16 + g * 4 + r][col] = f2bf(acc[mf][nf][r] + bs);
  }
  __syncthreads();

  // fragment-linear emit (sigma for K, transpose for V)
  u16* outF = (sel ? VF : KF) + (size_t)bm * 4096;
#pragma unroll
  for (int p = 0; p < 2; ++p) {
    const int id = tid + p * 256;          // (sub,ks,lane)
    const int sub = id >> 8, ks = (id >> 6) & 3, ln = id & 63;
    const int hi2 = ln >> 5, q = ln & 31;
    if (!sel) {   // K: sigma = swap bits 2<->3 of q
      const int sq = (q & ~12) | ((q & 4) << 1) | ((q & 8) >> 1);
      *(bf16x8*)&outF[id * 8] =
          *(const bf16x8*)&sm.stage[sub * 32 + sq][ks * 16 + hi2 * 8];
    } else {      // V: transposed
      u16 tmp[8];
#pragma unroll
      for (int i = 0; i < 8; ++i)
        tmp[i] = sm.stage[ks * 16 + hi2 * 8 + i][sub * 32 + q];
      *(bf16x8*)&outF[id * 8] = *(const bf16x8*)tmp;
    }
  }
}

// ---------------- 2-phase double-buffered 128x64 bf16 GEMM body, BK=64 ----------------
template <int OUT_F32>
DEV void gemm_dev(GemmSmem& sm,
                  const u16* __restrict__ A, const u16* __restrict__ BT,
                  const float* __restrict__ bias, void* __restrict__ Cout,
                  int M, int N, int K, float oscale, int bm, int bn) {
  const int tid = threadIdx.x, wave = tid >> 6, lane = tid & 63;
  const int wm = wave >> 1, wn = wave & 1;
  const int g = lane >> 4, c = lane & 15;
  f32x4 acc[4][2] = {};

  // staging maps (16B bf16 slots, source col pre-swizzled; linear LDS dest)
  int arow[4], acol[4], brow[2], bcol[2];
#pragma unroll
  for (int i = 0; i < 4; ++i) {
    const int sid = (i * 4 + wave) * 64 + lane;   // 0..1023
    arow[i] = sid >> 3;
    acol[i] = ((sid & 7) ^ ((sid >> 3) & 7)) * 8;
  }
#pragma unroll
  for (int i = 0; i < 2; ++i) {
    const int sid = (i * 4 + wave) * 64 + lane;   // 0..511
    brow[i] = sid >> 3;
    bcol[i] = ((sid & 7) ^ ((sid >> 3) & 7)) * 8;
  }
  const int nt = K >> 6;

  auto stage_g = [&](int buf, int t) {
    const int k0_ = t << 6;
#pragma unroll
    for (int i = 0; i < 4; ++i)
      gload_lds16(A + (size_t)(bm * 128 + arow[i]) * K + k0_ + acol[i],
                  &sm.At[buf][(i * 4 + wave) * 512]);
#pragma unroll
    for (int i = 0; i < 2; ++i)
      gload_lds16(BT + (size_t)(bn * 64 + brow[i]) * K + k0_ + bcol[i],
                  &sm.Bt[buf][(i * 4 + wave) * 512]);
  };

  stage_g(0, 0);
  asm volatile("s_waitcnt vmcnt(0)" ::: "memory");
  __syncthreads();

  int cur = 0;
  for (int t = 0; t < nt; ++t) {
    if (t + 1 < nt) stage_g(cur ^ 1, t + 1);   // issue next-tile loads FIRST
#pragma unroll
    for (int kk = 0; kk < 2; ++kk) {
      bf16x8 af[4], bfr[2];
#pragma unroll
      for (int mf = 0; mf < 4; ++mf) {
        const int row = wm * 64 + mf * 16 + c;
        af[mf] = *(const bf16x8*)(&sm.At[cur][row * 64 + ((kk * 4 + g) ^ (row & 7)) * 8]);
      }
#pragma unroll
      for (int nf = 0; nf < 2; ++nf) {
        const int row = wn * 32 + nf * 16 + c;
        bfr[nf] = *(const bf16x8*)(&sm.Bt[cur][row * 64 + ((kk * 4 + g) ^ (row & 7)) * 8]);
      }
#pragma unroll
      for (int mf = 0; mf < 4; ++mf)
#pragma unroll
        for (int nf = 0; nf < 2; ++nf)
          acc[mf][nf] = __builtin_amdgcn_mfma_f32_16x16x32_bf16(
              af[mf], bfr[nf], acc[mf][nf], 0, 0, 0);
    }
    asm volatile("s_waitcnt vmcnt(0)" ::: "memory");  // next tile landed
    __syncthreads();
    cur ^= 1;
  }

  const int colb = bn * 64 + wn * 32 + c;
  const int rowb = bm * 128 + wm * 64 + g * 4;
#pragma unroll
  for (int nf = 0; nf < 2; ++nf) {
    float bs = bias[colb + nf * 16];
#pragma unroll
    for (int mf = 0; mf < 4; ++mf) {
#pragma unroll
      for (int r = 0; r < 4; ++r) {
        size_t idx = (size_t)(rowb + mf * 16 + r) * N + colb + nf * 16;
        float v = (acc[mf][nf][r] + bs) * oscale;
        if (OUT_F32) ((float*)Cout)[idx] = v;
        else         ((u16*)Cout)[idx]   = f2bf(v);
      }
    }
  }
}

// ---------------- fused Q-GEMM + K/V projection: one 640-block dispatch ----------------
__global__ __launch_bounds__(256) void qkv_fused_kernel(
    const u16* __restrict__ Xq, const u16* __restrict__ WqT,
    const float* __restrict__ bq, u16* __restrict__ Qbf, float qscale,
    const float* __restrict__ Xk, const float* __restrict__ Xv,
    const u16* __restrict__ WkT, const u16* __restrict__ WvT,
    const float* __restrict__ bk, const float* __restrict__ bv,
    u16* __restrict__ KF, u16* __restrict__ VF) {
  __shared__ QkvSmem sm;
  if (blockIdx.y < 16) {
    gemm_dev<0>(sm.g, Xq, WqT, bq, Qbf, M_, DM, DM, qscale,
                blockIdx.x, blockIdx.y);
  } else {
    const int id = (blockIdx.y - 16) * 32 + blockIdx.x;   // 0..127
    const int sel = id >> 6, bm = id & 63;
    kvproj_dev(sm.kv, sel ? Xv : Xk, sel ? WvT : WkT, sel ? bv : bk,
               KF, VF, bm, sel);
  }
}

// ---------------- standalone GEMM kernel (O projection) ----------------
template <int OUT_F32>
__global__ __launch_bounds__(256) void gemm_bf16_kernel(
    const u16* __restrict__ A, const u16* __restrict__ BT,
    const float* __restrict__ bias, void* __restrict__ Cout,
    int M, int N, int K, float oscale) {
  __shared__ GemmSmem sm;
  gemm_dev<OUT_F32>(sm, A, BT, bias, Cout, M, N, K, oscale,
                    blockIdx.x, blockIdx.y);
}

// ---------------- attn: per-tile load / compute building blocks (R14 proven) ----------------
DEV void attn_load(const u16* kp, const u16* vp, bf16x8* kf, bf16x8* vf) {
#pragma unroll
  for (int i = 0; i < 4; ++i) {
    kf[i]     = *(const bf16x8*)(kp + i * 512);
    kf[4 + i] = *(const bf16x8*)(kp + 2048 + i * 512);
    vf[i]     = *(const bf16x8*)(vp + i * 512);
    vf[4 + i] = *(const bf16x8*)(vp + 2048 + i * 512);
  }
}

DEV void attn_comp(int t, int qrow, int hi, bool evenU, int nt,
                   const bf16x8* kf, const bf16x8* vf, const bf16x8* qf,
                   f32x16& acc0, f32x16& acc1, float& l_) {
  const int kv0 = t * 64;
  const bool diag = (t == nt - 1);
  const bool skipHi = diag && evenU;

  f32x16 sf0 = {}, sf1 = {};
  __builtin_amdgcn_s_setprio(1);
#pragma unroll
  for (int ks = 0; ks < 4; ++ks)
    sf0 = __builtin_amdgcn_mfma_f32_32x32x16_bf16(kf[ks], qf[ks], sf0, 0, 0, 0);
  if (!skipHi) {
#pragma unroll
    for (int ks = 0; ks < 4; ++ks)
      sf1 = __builtin_amdgcn_mfma_f32_32x32x16_bf16(kf[4 + ks], qf[ks], sf1, 0, 0, 0);
  }
  __builtin_amdgcn_s_setprio(0);

  if (diag) {   // causal mask; kv of reg r = 16*(r>>3) + 8*hi + (r&7)
#pragma unroll
    for (int r = 0; r < 16; ++r) {
      const int kvl = (r & 7) + 8 * hi + 16 * (r >> 3);
      if (kv0 + kvl > qrow)      sf0[r] = -1e30f;
      if (kv0 + 32 + kvl > qrow) sf1[r] = -1e30f;
    }
  }

  float rs0 = 0.f, rs1 = 0.f;
#pragma unroll
  for (int r = 0; r < 8; ++r)  { float e = EXP2(sf0[r]); sf0[r] = e; rs0 += e; }
#pragma unroll
  for (int r = 8; r < 16; ++r) { float e = EXP2(sf0[r]); sf0[r] = e; rs1 += e; }
  if (!skipHi) {
#pragma unroll
    for (int r = 0; r < 8; ++r)  { float e = EXP2(sf1[r]); sf1[r] = e; rs0 += e; }
#pragma unroll
    for (int r = 8; r < 16; ++r) { float e = EXP2(sf1[r]); sf1[r] = e; rs1 += e; }
  }
  l_ += rs0 + rs1;

  __builtin_amdgcn_s_setprio(1);
#pragma unroll
  for (int at = 0; at < 2; ++at) {
    if (at == 1 && skipHi) break;
    const f32x16& sfv = at ? sf1 : sf0;
#pragma unroll
    for (int half = 0; half < 2; ++half) {
      const int rb = half * 8;
      u32x4 pw;
      pw[0] = cvtpk_hw(sfv[rb + 0], sfv[rb + 1]);
      pw[1] = cvtpk_hw(sfv[rb + 2], sfv[rb + 3]);
      pw[2] = cvtpk_hw(sfv[rb + 4], sfv[rb + 5]);
      pw[3] = cvtpk_hw(sfv[rb + 6], sfv[rb + 7]);
      const bf16x8 pa = __builtin_bit_cast(bf16x8, pw);
      const int ksg = at * 2 + half;
      acc0 = __builtin_amdgcn_mfma_f32_32x32x16_bf16(pa, vf[ksg], acc0, 0, 0, 0);
      acc1 = __builtin_amdgcn_mfma_f32_32x32x16_bf16(pa, vf[4 + ksg], acc1, 0, 0, 0);
    }
  }
  __builtin_amdgcn_s_setprio(0);
}

// ---------------- causal MQA flash attention: split-KV, 2-wave blocks ----------------
// grid (H, 64, B): h = blockIdx.x (fastest), j = blockIdx.y. A CU's 8 blocks
// share j0 = j&15 with j in {j0, j0+16, j0+32, j0+48}. The u-mapping below
// assigns those four j's the causal units {j0, 31-j0, 32+j0, 63-j0}: the
// per-CU tile sum is EXACTLY 66 per 4-group (132 total) for every j0 ->
// perfectly balanced causal work across CUs (bijective permutation).
__global__ __launch_bounds__(128, 2) void attn_kernel(
    const u16* __restrict__ Q,   // [B*S][DM] bf16 (head h at col h*64), pre-scaled
    const u16* __restrict__ KF,  // fragment-linear K (sigma-permuted rows)
    const u16* __restrict__ VF,  // fragment-linear V
    u16* __restrict__ O) {       // [B*S][DM] bf16
  __shared__ float Ll[2][32];
  __shared__ float Lacc[2][32][64];   // 16 KB

  const int h = blockIdx.x, j = blockIdx.y, b = blockIdx.z;
  const int wave = threadIdx.x >> 6, lane = threadIdx.x & 63;
  const int q31 = lane & 31, hi = lane >> 5;

  const int j0 = j & 15, kb = j >> 4;
  const int u = (kb == 0) ? j0 : (kb == 1) ? (31 - j0)
              : (kb == 2) ? (32 + j0) : (63 - j0);
  const int qrow = u * 32 + q31;
  const int nt = (u + 2) >> 1;           // kv tiles for this q-unit
  const bool evenU = !(u & 1);

  const u16* Qp = Q + (size_t)(b * S_ + qrow) * DM + h * DK;
  bf16x8 qf[4];
#pragma unroll
  for (int ks = 0; ks < 4; ++ks)
    qf[ks] = *(const bf16x8*)(Qp + ks * 16 + hi * 8);

  f32x16 acc0 = {}, acc1 = {};
  float l_ = 0.f;

  const u16* kfb = KF + (size_t)(b * 32) * 4096 + lane * 8;
  const u16* vfb = VF + (size_t)(b * 32) * 4096 + lane * 8;

  bf16x8 kA[8], vA[8], kB[8], vB[8];
  int t = wave;
  if (t < nt)
    attn_load(kfb + (size_t)t * 4096, vfb + (size_t)t * 4096, kA, vA);
  for (; t < nt; t += 4) {
    const int t1 = t + 2;
    if (t1 < nt)
      attn_load(kfb + (size_t)t1 * 4096, vfb + (size_t)t1 * 4096, kB, vB);
    attn_comp(t, qrow, hi, evenU, nt, kA, vA, qf, acc0, acc1, l_);
    if (t1 < nt) {
      const int t2 = t1 + 2;
      if (t2 < nt)
        attn_load(kfb + (size_t)t2 * 4096, vfb + (size_t)t2 * 4096, kA, vA);
      attn_comp(t1, qrow, hi, evenU, nt, kB, vB, qf, acc0, acc1, l_);
    }
  }

  // one lane^32 combine of the per-lane l partials
  l_ += __shfl_xor(l_, 32);

  // ---- block-level combine of the 2 partials (plain sums) ----
  if (hi == 0) Ll[wave][q31] = l_;
  __syncthreads();

#pragma unroll
  for (int r = 0; r < 16; ++r) {
    const int rr = (r & 3) + 8 * (r >> 2) + 4 * hi;   // acc row (PV D layout)
    Lacc[wave][rr][q31]      = acc0[r];
    Lacc[wave][rr][32 + q31] = acc1[r];
  }
  __syncthreads();

  // 128 threads: row = tid>>2 (32 rows), dv0 = (tid&3)*16, 16 elems each
  const int tid = threadIdx.x;
  const int row = tid >> 2;
  const int dv0 = (tid & 3) * 16;
  const float Lr = Ll[0][row] + Ll[1][row];
  const float linv = 1.f / Lr;
  u16 ov[16];
#pragma unroll
  for (int i = 0; i < 16; ++i) {
    const float v = (Lacc[0][row][dv0 + i] + Lacc[1][row][dv0 + i]) * linv;
    ov[i] = f2bf(v);
  }
  u16* Op = O + (size_t)(b * S_ + u * 32 + row) * DM + h * DK + dv0;
  *(bf16x8*)Op       = *(const bf16x8*)ov;
  *(bf16x8*)(Op + 8) = *(const bf16x8*)(ov + 8);
}

// ---------------- launch ----------------
extern "C" void kernel_launch(void* const* d_in, const int* in_sizes, int n_in,
                              void* d_out, int out_size, void* d_ws, size_t ws_size,
                              hipStream_t stream) {
  const float* in_q = (const float*)d_in[0];
  const float* in_k = (const float*)d_in[1];
  const float* in_v = (const float*)d_in[2];
  const float* Wq   = (const float*)d_in[3];
  const float* bq   = (const float*)d_in[4];
  const float* Wk   = (const float*)d_in[5];
  const float* bk   = (const float*)d_in[6];
  const float* Wv   = (const float*)d_in[7];
  const float* bv   = (const float*)d_in[8];
  const float* Wo   = (const float*)d_in[9];
  const float* bo   = (const float*)d_in[10];

  char* ws  = (char*)d_ws;
  u16* Qbf  = (u16*)(ws + OFF_QBF);
  u16* KFp  = (u16*)(ws + OFF_KF);
  u16* VFp  = (u16*)(ws + OFF_VF);
  u16* AObf = (u16*)(ws + OFF_AOBF);
  u16* WqT  = (u16*)(ws + OFF_WQT);
  u16* WoT  = (u16*)(ws + OFF_WOT);
  u16* WkT  = (u16*)(ws + OFF_WKT);
  u16* WvT  = (u16*)(ws + OFF_WVT);
  u16* Xqbf = (u16*)(ws + OFF_XQBF);

  // one launch: all weight transposes + in_q cast
  prep_kernel<<<dim3(32, 32, 5), dim3(32, 8), 0, stream>>>(
      Wq, Wo, Wk, Wv, in_q, WqT, WoT, WkT, WvT, Xqbf);

  // one launch: Q projection (bf16 A, pre-scaled 1/8*log2e) + K/V projection
  qkv_fused_kernel<<<dim3(32, 20), 256, 0, stream>>>(
      Xqbf, WqT, bq, Qbf, 0.125f * 1.44269504088896f,
      in_k, in_v, WkT, WvT, bk, bv, KFp, VFp);

  attn_kernel<<<dim3(H_, 64, B_), 128, 0, stream>>>(Qbf, KFp, VFp, AObf);

  gemm_bf16_kernel<1><<<dim3(M_ / 128, DM / 64), 256, 0, stream>>>(
      AObf, WoT, bo, d_out, M_, DM, DM, 1.0f);
}

// Round 29
// 82.293 us; speedup vs baseline: 1.0511x; 1.0511x over previous
//
#include <hip/hip_runtime.h>
#include <cstdint>
#include <cstddef>

typedef unsigned short u16;
typedef __bf16 bf16x8 __attribute__((ext_vector_type(8)));
typedef float  f32x4  __attribute__((ext_vector_type(4)));
typedef float  f32x16 __attribute__((ext_vector_type(16)));
typedef unsigned u32x4 __attribute__((ext_vector_type(4)));

#define DEV __device__ __forceinline__

#define B_  2
#define S_  2048
#define DM  1024
#define H_  16
#define DK  64
#define M_  (B_ * S_)   // 4096

#if __has_builtin(__builtin_amdgcn_exp2f)
#define EXP2(x) __builtin_amdgcn_exp2f(x)
#else
#define EXP2(x) exp2f(x)
#endif

// ---------------- workspace layout (bytes) ----------------
constexpr size_t OFF_QBF  = 0;                                  // Q proj out bf16 [M][DM]
constexpr size_t OFF_KF   = OFF_QBF  + (size_t)M_ * DM * 2;     // K frag-linear (sigma rows)
constexpr size_t OFF_VF   = OFF_KF   + (size_t)M_ * DK * 2;     // V frag-linear
constexpr size_t OFF_AOBF = OFF_VF   + (size_t)M_ * DK * 2;     // attn out bf16 [M][DM]
constexpr size_t OFF_WQT  = OFF_AOBF + (size_t)M_ * DM * 2;     // Wq^T bf16 [DM][DM]
constexpr size_t OFF_WOT  = OFF_WQT  + (size_t)DM * DM * 2;     // Wo^T bf16 [DM][DM]
constexpr size_t OFF_WKT  = OFF_WOT  + (size_t)DM * DM * 2;     // Wk^T bf16 [DK][DM]
constexpr size_t OFF_WVT  = OFF_WKT  + (size_t)DK * DM * 2;     // Wv^T bf16 [DK][DM]
constexpr size_t OFF_XQBF = OFF_WVT  + (size_t)DK * DM * 2;     // inputs_q bf16 [M][DM]

// ---------------- helpers ----------------
DEV u16 f2bf(float f) {                 // RNE f32 -> bf16
  unsigned u = __float_as_uint(f);
  u += 0x7fffu + ((u >> 16) & 1u);
  return (u16)(u >> 16);
}

DEV unsigned cvtpk(float lo, float hi) { // pack 2 f32 -> 2 bf16 (lo in low 16)
  return (unsigned)f2bf(lo) | ((unsigned)f2bf(hi) << 16);
}

DEV unsigned cvtpk_hw(float lo, float hi) { // v_cvt_pk_bf16_f32 (1 instr)
  unsigned r;
  asm("v_cvt_pk_bf16_f32 %0, %1, %2" : "=v"(r) : "v"(lo), "v"(hi));
  return r;
}

DEV u32x4 pack8(const float4& a, const float4& b) {
  u32x4 w;
  w[0] = cvtpk(a.x, a.y);
  w[1] = cvtpk(a.z, a.w);
  w[2] = cvtpk(b.x, b.y);
  w[3] = cvtpk(b.z, b.w);
  return w;
}

DEV void gload_lds16(const void* g, void* l) {
  __builtin_amdgcn_global_load_lds(
      (const __attribute__((address_space(1))) unsigned int*)g,
      (__attribute__((address_space(3))) unsigned int*)l, 16, 0, 0);
}

// ---------------- shared-memory views for the fused qkv kernel ----------------
struct GemmSmem { u16 At[2][128 * 64]; u16 Bt[2][64 * 64]; };      // 48 KB
struct KvSmem   { u16 At[2][64 * 64]; u16 Bt[2][64 * 64]; u16 stage[64][72]; }; // ~41 KB
union QkvSmem { GemmSmem g; KvSmem kv; };

// ---------------- merged prep: 4 weight transposes + in_q cast, one launch ----------------
__global__ __launch_bounds__(256) void prep_kernel(
    const float* __restrict__ Wq, const float* __restrict__ Wo,
    const float* __restrict__ Wk, const float* __restrict__ Wv,
    const float* __restrict__ in_q,
    u16* __restrict__ WqT, u16* __restrict__ WoT,
    u16* __restrict__ WkT, u16* __restrict__ WvT,
    u16* __restrict__ Xq) {
  const int z = blockIdx.z;
  if (z == 4) {                        // cast in_q: 4M f32 -> bf16
    const int tid = (blockIdx.y * 32 + blockIdx.x) * 256 +
                    threadIdx.y * 32 + threadIdx.x;
    const int n8 = M_ * DM / 8;
    for (int i = tid; i < n8; i += 1024 * 256) {
      float4 a = ((const float4*)in_q)[2 * i];
      float4 b = ((const float4*)in_q)[2 * i + 1];
      ((u32x4*)Xq)[i] = pack8(a, b);
    }
    return;
  }
  const float* W; u16* WT; int C;
  if (z == 0)      { W = Wq; WT = WqT; C = DM; }
  else if (z == 1) { W = Wo; WT = WoT; C = DM; }
  else if (z == 2) { W = Wk; WT = WkT; C = DK; }
  else             { W = Wv; WT = WvT; C = DK; }
  const int c0 = blockIdx.x * 32, r0 = blockIdx.y * 32;
  if (c0 >= C) return;                 // block-uniform exit (Wk/Wv: only x<2)
  __shared__ u16 tile[32][33];
  for (int i = threadIdx.y; i < 32; i += 8)
    tile[i][threadIdx.x] = f2bf(W[(size_t)(r0 + i) * C + c0 + threadIdx.x]);
  __syncthreads();
  for (int i = threadIdx.y; i < 32; i += 8)
    WT[(size_t)(c0 + i) * DM + r0 + threadIdx.x] = tile[threadIdx.x][i];
}

// ---------------- K/V projection body: 2-phase dbuf BK=64, fused frag-linear emit ----------------
DEV void kvproj_dev(KvSmem& sm,
                    const float* __restrict__ X, const u16* __restrict__ WT,
                    const float* __restrict__ bias,
                    u16* __restrict__ KF, u16* __restrict__ VF,
                    int bm, int sel) {
  const int tid = threadIdx.x, wave = tid >> 6, lane = tid & 63;
  const int g = lane >> 4, c = lane & 15;
  const int wm = wave >> 1, wn = wave & 1;
  f32x4 acc[2][2] = {};

  // A: reg-staged f32 -> bf16, write-side XOR swizzle (8 slots of 8 bf16/row)
  const int row = tid >> 2, sd = tid & 3;
  const int s0 = sd, s1 = sd + 4;
  const float* Asrc = X + (size_t)(bm * 64 + row) * DM;
  const int d0 = row * 64 + ((s0 ^ (row & 7)) * 8);
  const int d1 = row * 64 + ((s1 ^ (row & 7)) * 8);
  float4 ar0, ar1, ar2, ar3;                       // 16 f32 in flight

  // B: gemm-style pre-swizzled-source gload_lds map (2 slots/thread)
  int brow[2], bcol[2];
#pragma unroll
  for (int i = 0; i < 2; ++i) {
    const int sid = (i * 4 + wave) * 64 + lane;    // 0..511
    brow[i] = sid >> 3;
    bcol[i] = ((sid & 7) ^ ((sid >> 3) & 7)) * 8;
  }

  auto loadA = [&](int t) {
    const float* p = Asrc + (t << 6);
    ar0 = *(const float4*)(p + s0 * 8);
    ar1 = *(const float4*)(p + s0 * 8 + 4);
    ar2 = *(const float4*)(p + s1 * 8);
    ar3 = *(const float4*)(p + s1 * 8 + 4);
  };
  auto writeA = [&](int buf) {
    *(u32x4*)&sm.At[buf][d0] = pack8(ar0, ar1);
    *(u32x4*)&sm.At[buf][d1] = pack8(ar2, ar3);
  };
  auto stageB = [&](int buf, int t) {
#pragma unroll
    for (int i = 0; i < 2; ++i)
      gload_lds16(WT + (size_t)brow[i] * DM + (t << 6) + bcol[i],
                  &sm.Bt[buf][(i * 4 + wave) * 512]);
  };

  const int nt = DM >> 6;   // 16
  loadA(0);
  stageB(0, 0);
  asm volatile("s_waitcnt vmcnt(0)" ::: "memory");
  writeA(0);
  __syncthreads();

  int cur = 0;
  for (int t = 0; t < nt; ++t) {
    if (t + 1 < nt) { stageB(cur ^ 1, t + 1); loadA(t + 1); }
#pragma unroll
    for (int kk = 0; kk < 2; ++kk) {
      bf16x8 af[2], bfr[2];
#pragma unroll
      for (int mf = 0; mf < 2; ++mf) {
        const int ra = wm * 32 + mf * 16 + c;
        af[mf] = *(const bf16x8*)(&sm.At[cur][ra * 64 + ((kk * 4 + g) ^ (ra & 7)) * 8]);
      }
#pragma unroll
      for (int nf = 0; nf < 2; ++nf) {
        const int rb = wn * 32 + nf * 16 + c;
        bfr[nf] = *(const bf16x8*)(&sm.Bt[cur][rb * 64 + ((kk * 4 + g) ^ (rb & 7)) * 8]);
      }
#pragma unroll
      for (int mf = 0; mf < 2; ++mf)
#pragma unroll
        for (int nf = 0; nf < 2; ++nf)
          acc[mf][nf] = __builtin_amdgcn_mfma_f32_16x16x32_bf16(
              af[mf], bfr[nf], acc[mf][nf], 0, 0, 0);
    }
    asm volatile("s_waitcnt vmcnt(0)" ::: "memory");  // next B tile landed
    if (t + 1 < nt) writeA(cur ^ 1);
    __syncthreads();
    cur ^= 1;
  }

  // stage D-layout output (bias added) into LDS
#pragma unroll
  for (int nf = 0; nf < 2; ++nf) {
    const int col = wn * 32 + nf * 16 + c;
    const float bs = bias[col];
#pragma unroll
    for (int mf = 0; mf < 2; ++mf)
#pragma unroll
      for (int r = 0; r < 4; ++r)
        sm.stage[wm * 32 + mf * 16 + g * 4 + r][col] = f2bf(acc[mf][nf][r] + bs);
  }
  __syncthreads();

  // fragment-linear emit (sigma for K, transpose for V)
  u16* outF = (sel ? VF : KF) + (size_t)bm * 4096;
#pragma unroll
  for (int p = 0; p < 2; ++p) {
    const int id = tid + p * 256;          // (sub,ks,lane)
    const int sub = id >> 8, ks = (id >> 6) & 3, ln = id & 63;
    const int hi2 = ln >> 5, q = ln & 31;
    if (!sel) {   // K: sigma = swap bits 2<->3 of q
      const int sq = (q & ~12) | ((q & 4) << 1) | ((q & 8) >> 1);
      *(bf16x8*)&outF[id * 8] =
          *(const bf16x8*)&sm.stage[sub * 32 + sq][ks * 16 + hi2 * 8];
    } else {      // V: transposed
      u16 tmp[8];
#pragma unroll
      for (int i = 0; i < 8; ++i)
        tmp[i] = sm.stage[ks * 16 + hi2 * 8 + i][sub * 32 + q];
      *(bf16x8*)&outF[id * 8] = *(const bf16x8*)tmp;
    }
  }
}

// ---------------- 2-phase double-buffered 128x64 bf16 GEMM body, BK=64 ----------------
template <int OUT_F32>
DEV void gemm_dev(GemmSmem& sm,
                  const u16* __restrict__ A, const u16* __restrict__ BT,
                  const float* __restrict__ bias, void* __restrict__ Cout,
                  int M, int N, int K, float oscale, int bm, int bn) {
  const int tid = threadIdx.x, wave = tid >> 6, lane = tid & 63;
  const int wm = wave >> 1, wn = wave & 1;
  const int g = lane >> 4, c = lane & 15;
  f32x4 acc[4][2] = {};

  // staging maps (16B bf16 slots, source col pre-swizzled; linear LDS dest)
  int arow[4], acol[4], brow[2], bcol[2];
#pragma unroll
  for (int i = 0; i < 4; ++i) {
    const int sid = (i * 4 + wave) * 64 + lane;   // 0..1023
    arow[i] = sid >> 3;
    acol[i] = ((sid & 7) ^ ((sid >> 3) & 7)) * 8;
  }
#pragma unroll
  for (int i = 0; i < 2; ++i) {
    const int sid = (i * 4 + wave) * 64 + lane;   // 0..511
    brow[i] = sid >> 3;
    bcol[i] = ((sid & 7) ^ ((sid >> 3) & 7)) * 8;
  }
  const int nt = K >> 6;

  auto stage_g = [&](int buf, int t) {
    const int k0_ = t << 6;
#pragma unroll
    for (int i = 0; i < 4; ++i)
      gload_lds16(A + (size_t)(bm * 128 + arow[i]) * K + k0_ + acol[i],
                  &sm.At[buf][(i * 4 + wave) * 512]);
#pragma unroll
    for (int i = 0; i < 2; ++i)
      gload_lds16(BT + (size_t)(bn * 64 + brow[i]) * K + k0_ + bcol[i],
                  &sm.Bt[buf][(i * 4 + wave) * 512]);
  };

  stage_g(0, 0);
  asm volatile("s_waitcnt vmcnt(0)" ::: "memory");
  __syncthreads();

  int cur = 0;
  for (int t = 0; t < nt; ++t) {
    if (t + 1 < nt) stage_g(cur ^ 1, t + 1);   // issue next-tile loads FIRST
#pragma unroll
    for (int kk = 0; kk < 2; ++kk) {
      bf16x8 af[4], bfr[2];
#pragma unroll
      for (int mf = 0; mf < 4; ++mf) {
        const int row = wm * 64 + mf * 16 + c;
        af[mf] = *(const bf16x8*)(&sm.At[cur][row * 64 + ((kk * 4 + g) ^ (row & 7)) * 8]);
      }
#pragma unroll
      for (int nf = 0; nf < 2; ++nf) {
        const int row = wn * 32 + nf * 16 + c;
        bfr[nf] = *(const bf16x8*)(&sm.Bt[cur][row * 64 + ((kk * 4 + g) ^ (row & 7)) * 8]);
      }
#pragma unroll
      for (int mf = 0; mf < 4; ++mf)
#pragma unroll
        for (int nf = 0; nf < 2; ++nf)
          acc[mf][nf] = __builtin_amdgcn_mfma_f32_16x16x32_bf16(
              af[mf], bfr[nf], acc[mf][nf], 0, 0, 0);
    }
    asm volatile("s_waitcnt vmcnt(0)" ::: "memory");  // next tile landed
    __syncthreads();
    cur ^= 1;
  }

  const int colb = bn * 64 + wn * 32 + c;
  const int rowb = bm * 128 + wm * 64 + g * 4;
#pragma unroll
  for (int nf = 0; nf < 2; ++nf) {
    float bs = bias[colb + nf * 16];
#pragma unroll
    for (int mf = 0; mf < 4; ++mf) {
#pragma unroll
      for (int r = 0; r < 4; ++r) {
        size_t idx = (size_t)(rowb + mf * 16 + r) * N + colb + nf * 16;
        float v = (acc[mf][nf][r] + bs) * oscale;
        if (OUT_F32) ((float*)Cout)[idx] = v;
        else         ((u16*)Cout)[idx]   = f2bf(v);
      }
    }
  }
}

// ---------------- fused Q-GEMM + K/V projection: one 640-block dispatch ----------------
__global__ __launch_bounds__(256) void qkv_fused_kernel(
    const u16* __restrict__ Xq, const u16* __restrict__ WqT,
    const float* __restrict__ bq, u16* __restrict__ Qbf, float qscale,
    const float* __restrict__ Xk, const float* __restrict__ Xv,
    const u16* __restrict__ WkT, const u16* __restrict__ WvT,
    const float* __restrict__ bk, const float* __restrict__ bv,
    u16* __restrict__ KF, u16* __restrict__ VF) {
  __shared__ QkvSmem sm;
  if (blockIdx.y < 16) {
    gemm_dev<0>(sm.g, Xq, WqT, bq, Qbf, M_, DM, DM, qscale,
                blockIdx.x, blockIdx.y);
  } else {
    const int id = (blockIdx.y - 16) * 32 + blockIdx.x;   // 0..127
    const int sel = id >> 6, bm = id & 63;
    kvproj_dev(sm.kv, sel ? Xv : Xk, sel ? WvT : WkT, sel ? bv : bk,
               KF, VF, bm, sel);
  }
}

// ---------------- standalone GEMM kernel (O projection) ----------------
template <int OUT_F32>
__global__ __launch_bounds__(256) void gemm_bf16_kernel(
    const u16* __restrict__ A, const u16* __restrict__ BT,
    const float* __restrict__ bias, void* __restrict__ Cout,
    int M, int N, int K, float oscale) {
  __shared__ GemmSmem sm;
  gemm_dev<OUT_F32>(sm, A, BT, bias, Cout, M, N, K, oscale,
                    blockIdx.x, blockIdx.y);
}

// ---------------- attn: per-tile load / compute building blocks (R14 proven) ----------------
DEV void attn_load(const u16* kp, const u16* vp, bf16x8* kf, bf16x8* vf) {
#pragma unroll
  for (int i = 0; i < 4; ++i) {
    kf[i]     = *(const bf16x8*)(kp + i * 512);
    kf[4 + i] = *(const bf16x8*)(kp + 2048 + i * 512);
    vf[i]     = *(const bf16x8*)(vp + i * 512);
    vf[4 + i] = *(const bf16x8*)(vp + 2048 + i * 512);
  }
}

DEV void attn_comp(int t, int qrow, int hi, bool evenU, int nt,
                   const bf16x8* kf, const bf16x8* vf, const bf16x8* qf,
                   f32x16& acc0, f32x16& acc1, float& l_) {
  const int kv0 = t * 64;
  const bool diag = (t == nt - 1);
  const bool skipHi = diag && evenU;

  f32x16 sf0 = {}, sf1 = {};
  __builtin_amdgcn_s_setprio(1);
#pragma unroll
  for (int ks = 0; ks < 4; ++ks)
    sf0 = __builtin_amdgcn_mfma_f32_32x32x16_bf16(kf[ks], qf[ks], sf0, 0, 0, 0);
  if (!skipHi) {
#pragma unroll
    for (int ks = 0; ks < 4; ++ks)
      sf1 = __builtin_amdgcn_mfma_f32_32x32x16_bf16(kf[4 + ks], qf[ks], sf1, 0, 0, 0);
  }
  __builtin_amdgcn_s_setprio(0);

  if (diag) {   // causal mask; kv of reg r = 16*(r>>3) + 8*hi + (r&7)
#pragma unroll
    for (int r = 0; r < 16; ++r) {
      const int kvl = (r & 7) + 8 * hi + 16 * (r >> 3);
      if (kv0 + kvl > qrow)      sf0[r] = -1e30f;
      if (kv0 + 32 + kvl > qrow) sf1[r] = -1e30f;
    }
  }

  float rs0 = 0.f, rs1 = 0.f;
#pragma unroll
  for (int r = 0; r < 8; ++r)  { float e = EXP2(sf0[r]); sf0[r] = e; rs0 += e; }
#pragma unroll
  for (int r = 8; r < 16; ++r) { float e = EXP2(sf0[r]); sf0[r] = e; rs1 += e; }
  if (!skipHi) {
#pragma unroll
    for (int r = 0; r < 8; ++r)  { float e = EXP2(sf1[r]); sf1[r] = e; rs0 += e; }
#pragma unroll
    for (int r = 8; r < 16; ++r) { float e = EXP2(sf1[r]); sf1[r] = e; rs1 += e; }
  }
  l_ += rs0 + rs1;

  __builtin_amdgcn_s_setprio(1);
#pragma unroll
  for (int at = 0; at < 2; ++at) {
    if (at == 1 && skipHi) break;
    const f32x16& sfv = at ? sf1 : sf0;
#pragma unroll
    for (int half = 0; half < 2; ++half) {
      const int rb = half * 8;
      u32x4 pw;
      pw[0] = cvtpk_hw(sfv[rb + 0], sfv[rb + 1]);
      pw[1] = cvtpk_hw(sfv[rb + 2], sfv[rb + 3]);
      pw[2] = cvtpk_hw(sfv[rb + 4], sfv[rb + 5]);
      pw[3] = cvtpk_hw(sfv[rb + 6], sfv[rb + 7]);
      const bf16x8 pa = __builtin_bit_cast(bf16x8, pw);
      const int ksg = at * 2 + half;
      acc0 = __builtin_amdgcn_mfma_f32_32x32x16_bf16(pa, vf[ksg], acc0, 0, 0, 0);
      acc1 = __builtin_amdgcn_mfma_f32_32x32x16_bf16(pa, vf[4 + ksg], acc1, 0, 0, 0);
    }
  }
  __builtin_amdgcn_s_setprio(0);
}

// ---------------- causal MQA flash attention: split-KV, 2-wave blocks ----------------
// grid (H, 64, B): h = blockIdx.x (FASTEST dim), j = blockIdx.y. Round-robin
// block->CU assignment strides the linear ID by #CUs (256); with h fastest,
// each CU receives 4 DISTINCT j values (spread by 16) instead of one repeated
// j (the old grid's 64-aliasing put all of a CU's blocks at the same causal
// depth -> ~1.9x makespan stretch). u = 63-j additionally gives LPT dispatch
// order (longest blocks launched first) which covers residual imbalance.
__global__ __launch_bounds__(128, 2) void attn_kernel(
    const u16* __restrict__ Q,   // [B*S][DM] bf16 (head h at col h*64), pre-scaled
    const u16* __restrict__ KF,  // fragment-linear K (sigma-permuted rows)
    const u16* __restrict__ VF,  // fragment-linear V
    u16* __restrict__ O) {       // [B*S][DM] bf16
  __shared__ float Ll[2][32];
  __shared__ float Lacc[2][32][64];   // 16 KB

  const int h = blockIdx.x, j = blockIdx.y, b = blockIdx.z;
  const int wave = threadIdx.x >> 6, lane = threadIdx.x & 63;
  const int q31 = lane & 31, hi = lane >> 5;

  const int u = 63 - j;                  // LPT order
  const int qrow = u * 32 + q31;
  const int nt = (u + 2) >> 1;           // kv tiles for this q-unit
  const bool evenU = !(u & 1);

  const u16* Qp = Q + (size_t)(b * S_ + qrow) * DM + h * DK;
  bf16x8 qf[4];
#pragma unroll
  for (int ks = 0; ks < 4; ++ks)
    qf[ks] = *(const bf16x8*)(Qp + ks * 16 + hi * 8);

  f32x16 acc0 = {}, acc1 = {};
  float l_ = 0.f;

  const u16* kfb = KF + (size_t)(b * 32) * 4096 + lane * 8;
  const u16* vfb = VF + (size_t)(b * 32) * 4096 + lane * 8;

  bf16x8 kA[8], vA[8], kB[8], vB[8];
  int t = wave;
  if (t < nt)
    attn_load(kfb + (size_t)t * 4096, vfb + (size_t)t * 4096, kA, vA);
  for (; t < nt; t += 4) {
    const int t1 = t + 2;
    if (t1 < nt)
      attn_load(kfb + (size_t)t1 * 4096, vfb + (size_t)t1 * 4096, kB, vB);
    attn_comp(t, qrow, hi, evenU, nt, kA, vA, qf, acc0, acc1, l_);
    if (t1 < nt) {
      const int t2 = t1 + 2;
      if (t2 < nt)
        attn_load(kfb + (size_t)t2 * 4096, vfb + (size_t)t2 * 4096, kA, vA);
      attn_comp(t1, qrow, hi, evenU, nt, kB, vB, qf, acc0, acc1, l_);
    }
  }

  // one lane^32 combine of the per-lane l partials
  l_ += __shfl_xor(l_, 32);

  // ---- block-level combine of the 2 partials (plain sums) ----
  if (hi == 0) Ll[wave][q31] = l_;
  __syncthreads();

#pragma unroll
  for (int r = 0; r < 16; ++r) {
    const int rr = (r & 3) + 8 * (r >> 2) + 4 * hi;   // acc row (PV D layout)
    Lacc[wave][rr][q31]      = acc0[r];
    Lacc[wave][rr][32 + q31] = acc1[r];
  }
  __syncthreads();

  // 128 threads: row = tid>>2 (32 rows), dv0 = (tid&3)*16, 16 elems each
  const int tid = threadIdx.x;
  const int row = tid >> 2;
  const int dv0 = (tid & 3) * 16;
  const float Lr = Ll[0][row] + Ll[1][row];
  const float linv = 1.f / Lr;
  u16 ov[16];
#pragma unroll
  for (int i = 0; i < 16; ++i) {
    const float v = (Lacc[0][row][dv0 + i] + Lacc[1][row][dv0 + i]) * linv;
    ov[i] = f2bf(v);
  }
  u16* Op = O + (size_t)(b * S_ + u * 32 + row) * DM + h * DK + dv0;
  *(bf16x8*)Op       = *(const bf16x8*)ov;
  *(bf16x8*)(Op + 8) = *(const bf16x8*)(ov + 8);
}

// ---------------- launch ----------------
extern "C" void kernel_launch(void* const* d_in, const int* in_sizes, int n_in,
                              void* d_out, int out_size, void* d_ws, size_t ws_size,
                              hipStream_t stream) {
  const float* in_q = (const float*)d_in[0];
  const float* in_k = (const float*)d_in[1];
  const float* in_v = (const float*)d_in[2];
  const float* Wq   = (const float*)d_in[3];
  const float* bq   = (const float*)d_in[4];
  const float* Wk   = (const float*)d_in[5];
  const float* bk   = (const float*)d_in[6];
  const float* Wv   = (const float*)d_in[7];
  const float* bv   = (const float*)d_in[8];
  const float* Wo   = (const float*)d_in[9];
  const float* bo   = (const float*)d_in[10];

  char* ws  = (char*)d_ws;
  u16* Qbf  = (u16*)(ws + OFF_QBF);
  u16* KFp  = (u16*)(ws + OFF_KF);
  u16* VFp  = (u16*)(ws + OFF_VF);
  u16* AObf = (u16*)(ws + OFF_AOBF);
  u16* WqT  = (u16*)(ws + OFF_WQT);
  u16* WoT  = (u16*)(ws + OFF_WOT);
  u16* WkT  = (u16*)(ws + OFF_WKT);
  u16* WvT  = (u16*)(ws + OFF_WVT);
  u16* Xqbf = (u16*)(ws + OFF_XQBF);

  // one launch: all weight transposes + in_q cast
  prep_kernel<<<dim3(32, 32, 5), dim3(32, 8), 0, stream>>>(
      Wq, Wo, Wk, Wv, in_q, WqT, WoT, WkT, WvT, Xqbf);

  // one launch: Q projection (bf16 A, pre-scaled 1/8*log2e) + K/V projection
  qkv_fused_kernel<<<dim3(32, 20), 256, 0, stream>>>(
      Xqbf, WqT, bq, Qbf, 0.125f * 1.44269504088896f,
      in_k, in_v, WkT, WvT, bk, bv, KFp, VFp);

  attn_kernel<<<dim3(H_, 64, B_), 128, 0, stream>>>(Qbf, KFp, VFp, AObf);

  gemm_bf16_kernel<1><<<dim3(M_ / 128, DM / 64), 256, 0, stream>>>(
      AObf, WoT, bo, d_out, M_, DM, DM, 1.0f);
}